// Round 10
// baseline (332.397 us; speedup 1.0000x reference)
//
#include <hip/hip_runtime.h>

// Problem: nearest = memory[argmax_m cosine(x_row, memory_m)], plus copy of x.
//   x: 65536 x 1024 f32, memory: 40 x 1024 f32, out = [nearest | x-copy]
//
// R10 = R9 (MFMA split-f32, validated absmax=0) + register double-buffering of
// BOTH A (x) and B (mem bf16 hi/lo) fragments: operands for step t+1 are
// issued at the top of step t, so MFMA(t) never waits on L2 (~250cy) or HBM.
// Also drops the al*bl MFMA pass (error ~1e-6 normalized << TAU): 9 MFMA/step.
//
// d_ws layout (bytes):
//   [0,      320) : double inv64[40]
//   [320,    480) : float  inv32[40]
//   [512,  16896) : uint flagbits[4096]  (16-bit mask per 16-row wave)
//   [32768,131072): ushort bhi[48][1024] (bf16 hi of mem*inv32, rows 40-47 = 0)
//   [131072,229376): ushort blo[48][1024] (bf16 lo)

#define DIM 1024
#define NMEM 40

typedef float  vf4 __attribute__((ext_vector_type(4)));
typedef float  f4a __attribute__((ext_vector_type(4)));
typedef short  s8v __attribute__((ext_vector_type(8)));

union FragU { s8v v; unsigned int u[4]; };

constexpr float TAU = 2.5e-4f;   // normalized top-2 gap below which f64 re-resolve

// ---------------- Kernel 1: memory-row inverse norms (f32 + f64) ----------------
__global__ __launch_bounds__(64) void k_norms(const float* __restrict__ mem,
                                              double* __restrict__ inv64,
                                              float* __restrict__ inv32) {
  const int m = blockIdx.x;      // 40 blocks, 1 wave each
  const int lane = threadIdx.x;
  const float* __restrict__ row = mem + (size_t)m * DIM;
  double s = 0.0;
#pragma unroll
  for (int i = 0; i < DIM / 64; ++i) {
    double v = (double)row[lane + 64 * i];
    s = fma(v, v, s);
  }
#pragma unroll
  for (int off = 32; off > 0; off >>= 1) s += __shfl_xor(s, off, 64);
  if (lane == 0) {
    double n = sqrt(s);
    n = (n > 1e-8) ? n : 1e-8;
    inv64[m] = 1.0 / n;
    inv32[m] = (float)(1.0 / n);
  }
}

// ---------------- Kernel 1b: split normalized memory into bf16 hi/lo ----------------
__global__ __launch_bounds__(256) void k_prep(const float* __restrict__ mem,
                                              const float* __restrict__ inv32,
                                              unsigned short* __restrict__ bhi,
                                              unsigned short* __restrict__ blo) {
  const int m = blockIdx.x;            // 0..47 (40 real + 8 zero-pad)
  const int k0 = threadIdx.x * 4;      // 1024/256 = 4 elems/thread
  if (m < NMEM) {
    const float s = inv32[m];
#pragma unroll
    for (int j = 0; j < 4; ++j) {
      float w = mem[(size_t)m * DIM + k0 + j] * s;
      unsigned int u = __builtin_bit_cast(unsigned int, w);
      bhi[(size_t)m * DIM + k0 + j] = (unsigned short)(u >> 16);
      float hf = __builtin_bit_cast(float, u & 0xFFFF0000u);
      float lo = w - hf;
      blo[(size_t)m * DIM + k0 + j] =
          (unsigned short)(__builtin_bit_cast(unsigned int, lo) >> 16);
    }
  } else {
#pragma unroll
    for (int j = 0; j < 4; ++j) {
      bhi[(size_t)m * DIM + k0 + j] = 0;
      blo[(size_t)m * DIM + k0 + j] = 0;
    }
  }
}

// ---------------- Kernel 2: MFMA sims + argmax + gather + x-copy ----------------
// Block = 256 thr = 4 independent waves (no barriers). Wave = 16 x-rows.
// A-frag (x): lane holds row (l&15), k-slice (l>>4)*8..+8. B-frag (mem): lane
// holds m-col (l&15)+16*tile, same k-slice. C (m89-verified): lane holds
// D[(l>>4)*4+j][(l&15)+16*tile]. A and B register-double-buffered: step t
// issues t+1's loads BEFORE computing with t's (resident) operands.
__global__ __launch_bounds__(256, 4) void k_main(const float* __restrict__ x,
                                                 const float* __restrict__ mem,
                                                 const unsigned short* __restrict__ bhi,
                                                 const unsigned short* __restrict__ blo,
                                                 float* __restrict__ out_near,
                                                 float* __restrict__ out_x,
                                                 unsigned int* __restrict__ flagbits) {
  __shared__ float nxw[4][16];
  __shared__ int   amaxw[4][16];
  __shared__ int   flagw[4][16];

  const int tid  = threadIdx.x;
  const int lane = tid & 63;
  const int w    = __builtin_amdgcn_readfirstlane(tid >> 6);
  const int row  = lane & 15;          // x-row within wave tile / m-col within tile
  const int kg   = lane >> 4;          // k-subslice group (0..3)
  const int rowbase = blockIdx.x * 64 + w * 16;

  const float* __restrict__ xp  = x     + (size_t)(rowbase + row) * DIM + kg * 8;
  float* __restrict__ oxp       = out_x + (size_t)(rowbase + row) * DIM + kg * 8;
  const unsigned short* __restrict__ bp = bhi + (size_t)row * DIM + kg * 8;
  const unsigned short* __restrict__ lp = blo + (size_t)row * DIM + kg * 8;

  f4a acc[3];
#pragma unroll
  for (int t = 0; t < 3; ++t) acc[t] = (f4a){0.f, 0.f, 0.f, 0.f};
  float nx = 0.f;

  // double-buffered operand registers
  vf4 A0a, A0b, A1a, A1b;
  s8v BH0[3], BL0[3], BH1[3], BL1[3];

  // prologue: step-0 operands
  A0a = *(const vf4*)(xp);
  A0b = *(const vf4*)(xp + 4);
#pragma unroll
  for (int tt = 0; tt < 3; ++tt) {
    BH0[tt] = *(const s8v*)(bp + (size_t)tt * 16 * DIM);
    BL0[tt] = *(const s8v*)(lp + (size_t)tt * 16 * DIM);
  }

  auto compute = [&](vf4 a0, vf4 a1, s8v (&bh)[3], s8v (&bl)[3], int t) {
    // x-copy from the same registers (x read exactly once)
    __builtin_nontemporal_store(a0, (vf4*)(oxp + t * 32));
    __builtin_nontemporal_store(a1, (vf4*)(oxp + t * 32 + 4));
    // ||x||^2 partial
    nx = fmaf(a0.x, a0.x, fmaf(a0.y, a0.y, fmaf(a0.z, a0.z, fmaf(a0.w, a0.w, nx))));
    nx = fmaf(a1.x, a1.x, fmaf(a1.y, a1.y, fmaf(a1.z, a1.z, fmaf(a1.w, a1.w, nx))));
    // split f32 -> hi/lo bf16 (truncation; residual ~2^-17)
    FragU ah, al;
    float f[8] = {a0.x, a0.y, a0.z, a0.w, a1.x, a1.y, a1.z, a1.w};
#pragma unroll
    for (int p = 0; p < 4; ++p) {
      unsigned int u0 = __builtin_bit_cast(unsigned int, f[2 * p]);
      unsigned int u1 = __builtin_bit_cast(unsigned int, f[2 * p + 1]);
      ah.u[p] = (u1 & 0xFFFF0000u) | (u0 >> 16);
      float h0 = __builtin_bit_cast(float, u0 & 0xFFFF0000u);
      float h1 = __builtin_bit_cast(float, u1 & 0xFFFF0000u);
      float l0 = f[2 * p] - h0;
      float l1 = f[2 * p + 1] - h1;
      al.u[p] = (__builtin_bit_cast(unsigned int, l1) & 0xFFFF0000u) |
                (__builtin_bit_cast(unsigned int, l0) >> 16);
    }
    // 3 split passes (al*bl dropped: ~1e-6 normalized) x 3 N-tiles
#pragma unroll
    for (int tt = 0; tt < 3; ++tt) {
      acc[tt] = __builtin_amdgcn_mfma_f32_16x16x32_bf16(ah.v, bh[tt], acc[tt], 0, 0, 0);
      acc[tt] = __builtin_amdgcn_mfma_f32_16x16x32_bf16(ah.v, bl[tt], acc[tt], 0, 0, 0);
      acc[tt] = __builtin_amdgcn_mfma_f32_16x16x32_bf16(al.v, bh[tt], acc[tt], 0, 0, 0);
    }
  };

#pragma unroll
  for (int t = 0; t < 32; t += 2) {
    // even step t: consume buf0, prefetch t+1 into buf1
    {
      A1a = *(const vf4*)(xp + (t + 1) * 32);
      A1b = *(const vf4*)(xp + (t + 1) * 32 + 4);
#pragma unroll
      for (int tt = 0; tt < 3; ++tt) {
        BH1[tt] = *(const s8v*)(bp + (size_t)tt * 16 * DIM + (t + 1) * 32);
        BL1[tt] = *(const s8v*)(lp + (size_t)tt * 16 * DIM + (t + 1) * 32);
      }
    }
    compute(A0a, A0b, BH0, BL0, t);
    // odd step t+1: consume buf1, prefetch t+2 into buf0
    if (t + 2 < 32) {
      A0a = *(const vf4*)(xp + (t + 2) * 32);
      A0b = *(const vf4*)(xp + (t + 2) * 32 + 4);
#pragma unroll
      for (int tt = 0; tt < 3; ++tt) {
        BH0[tt] = *(const s8v*)(bp + (size_t)tt * 16 * DIM + (t + 2) * 32);
        BL0[tt] = *(const s8v*)(lp + (size_t)tt * 16 * DIM + (t + 2) * 32);
      }
    }
    compute(A1a, A1b, BH1, BL1, t + 1);
  }

  // ||x||^2: sum the 4 k-groups (lanes l, l^16, l^32, l^48 share row l&15)
  nx += __shfl_xor(nx, 16, 64);
  nx += __shfl_xor(nx, 32, 64);
  if (lane < 16) nxw[w][lane] = nx;

  // per-lane top-2: lane holds sims for rows (l>>4)*4+j, m-cols (l&15)+16t
  float v1[4], v2[4];
  int   i1[4];
#pragma unroll
  for (int j = 0; j < 4; ++j) {
    float c0 = acc[0][j], c1 = acc[1][j];
    float c2 = (row < 8) ? acc[2][j] : -3.4e38f;   // cols 40-47 are pad
    float a1 = c0, a2 = -3.4e38f;
    int   ai = row;
    if (c1 > a1) { a2 = a1; a1 = c1; ai = row + 16; } else a2 = c1;
    if (c2 > a1) { a2 = a1; a1 = c2; ai = row + 32; } else if (c2 > a2) a2 = c2;
    v1[j] = a1; v2[j] = a2; i1[j] = ai;
  }
#pragma unroll
  for (int st = 1; st < 16; st <<= 1) {  // reduce over the 16 lanes of each row-group
#pragma unroll
    for (int j = 0; j < 4; ++j) {
      float o1 = __shfl_xor(v1[j], st, 64);
      float o2 = __shfl_xor(v2[j], st, 64);
      int   oi = __shfl_xor(i1[j], st, 64);
      if (o1 > v1[j]) { v2[j] = fmaxf(v1[j], o2); v1[j] = o1; i1[j] = oi; }
      else            { v2[j] = fmaxf(v2[j], o1); }           // tie -> gap 0 -> flagged
    }
  }
  if ((lane & 15) == 0) {
    const int g = lane >> 4;
#pragma unroll
    for (int j = 0; j < 4; ++j) {
      const int r = 4 * g + j;
      float gap = (v1[j] - v2[j]) * rsqrtf(fmaxf(nxw[w][r], 1e-30f));
      flagw[w][r] = !(gap >= TAU);     // NaN-safe
      amaxw[w][r] = i1[j];
    }
  }
  int flv = flagw[w][lane & 15];
  unsigned long long bmask = __ballot(flv != 0);
  if (lane == 0) flagbits[blockIdx.x * 4 + w] = (unsigned int)(bmask & 0xFFFFull);

  // gather-copy memory[amax] -> out_near (16 rows/wave, coalesced)
  const vf4* __restrict__ m4 = (const vf4*)mem;
#pragma unroll 1
  for (int r = 0; r < 16; ++r) {
    int am = __builtin_amdgcn_readfirstlane(amaxw[w][r]);
    const vf4* __restrict__ src = m4 + (size_t)am * (DIM / 4);
    vf4* __restrict__ dst = (vf4*)out_near + (size_t)(rowbase + r) * (DIM / 4);
#pragma unroll
    for (int j = 0; j < 4; ++j) {
      vf4 v = src[lane + 64 * j];
      __builtin_nontemporal_store(v, &dst[lane + 64 * j]);
    }
  }
}

// ---------------- Kernel 3: f64 re-resolution of razor-thin rows ----------------
__global__ __launch_bounds__(256) void k_refine(const float* __restrict__ x,
                                                const float* __restrict__ mem,
                                                const double* __restrict__ inv64,
                                                const unsigned int* __restrict__ flagbits,
                                                float* __restrict__ out_near) {
  unsigned int mask = flagbits[blockIdx.x];
  if (mask == 0u) return;                   // uniform; nearly all blocks exit
  const int tid = threadIdx.x;
  const int lane = tid & 63;
  const int wid = tid >> 6;
  __shared__ double bval[4];
  __shared__ int bidx[4];
  while (mask) {
    int r = __ffs(mask) - 1;
    mask &= (mask - 1u);
    int rrow = blockIdx.x * 16 + r;
    const float* __restrict__ xr = x + (size_t)rrow * DIM;
    double xd[16];
#pragma unroll
    for (int i = 0; i < 16; ++i) xd[i] = (double)xr[lane + 64 * i];
    double best = -1e300;
    int bi = 0;
    for (int q = 0; q < 10; ++q) {
      int m = wid * 10 + q;
      const float* __restrict__ mr = mem + (size_t)m * DIM;
      double s = 0.0;
#pragma unroll
      for (int i = 0; i < 16; ++i) s = fma(xd[i], (double)mr[lane + 64 * i], s);
#pragma unroll
      for (int off = 32; off > 0; off >>= 1) s += __shfl_xor(s, off, 64);
      double v = s * inv64[m];              // identical (bitwise) across lanes
      if (v > best) { best = v; bi = m; }   // strict > keeps lowest m on ties
    }
    if (lane == 0) { bval[wid] = best; bidx[wid] = bi; }
    __syncthreads();
    double g = bval[0];
    int gi = bidx[0];
#pragma unroll
    for (int gg = 1; gg < 4; ++gg) {
      if (bval[gg] > g) { g = bval[gg]; gi = bidx[gg]; }
    }
    const float4* __restrict__ src = (const float4*)mem + (size_t)gi * (DIM / 4);
    float4* __restrict__ dst = (float4*)out_near + (size_t)rrow * (DIM / 4);
    dst[tid] = src[tid];                    // 256 x 16B = full row, coalesced
    __syncthreads();                        // LDS reuse guard for next flagged row
  }
}

extern "C" void kernel_launch(void* const* d_in, const int* in_sizes, int n_in,
                              void* d_out, int out_size, void* d_ws, size_t ws_size,
                              hipStream_t stream) {
  const float* x   = (const float*)d_in[0];
  const float* mem = (const float*)d_in[1];
  // d_in[2] = top_k (unused: reference only consumes idx[:,0], i.e. the argmax)

  const int n_rows = in_sizes[0] / DIM;          // 65536
  float* out_near = (float*)d_out;
  float* out_x    = (float*)d_out + (size_t)n_rows * DIM;

  double* inv64 = (double*)d_ws;
  float*  inv32 = (float*)((char*)d_ws + 320);
  unsigned int* flagbits = (unsigned int*)((char*)d_ws + 512);
  unsigned short* bhi = (unsigned short*)((char*)d_ws + 32768);
  unsigned short* blo = (unsigned short*)((char*)d_ws + 131072);

  hipLaunchKernelGGL(k_norms, dim3(NMEM), dim3(64), 0, stream, mem, inv64, inv32);
  hipLaunchKernelGGL(k_prep,  dim3(48),   dim3(256), 0, stream, mem, inv32, bhi, blo);
  hipLaunchKernelGGL(k_main,  dim3(n_rows / 64), dim3(256), 0, stream,
                     x, mem, bhi, blo, out_near, out_x, flagbits);
  hipLaunchKernelGGL(k_refine, dim3(n_rows / 16), dim3(256), 0, stream,
                     x, mem, inv64, flagbits, out_near);
}

// Round 11
// 305.475 us; speedup vs baseline: 1.0881x; 1.0881x over previous
//
#include <hip/hip_runtime.h>

// Problem: nearest = memory[argmax_m cosine(x_row, memory_m)], plus copy of x.
//   x: 65536 x 1024 f32, memory: 40 x 1024 f32, out = [nearest | x-copy]
//
// R11 = R9 (MFMA split-f32, validated absmax=0, best: ~240us k_main) with ONE
// change: the x-copy stores are REGULAR stores (not nontemporal). R9's nt
// stores wrote 16B pieces at 4KB stride past L2 -> partial-line HBM writes on
// a 256MB stream. Regular stores let L2 merge the 4x32B pieces per row per
// K-step into full 128B lines. Gather stores stay nt (1KB contiguous/instr).
// R10's register double-buffer spilled (WRITE_SIZE +240MB) -> reverted.
//
// d_ws layout (bytes):
//   [0,      320) : double inv64[40]
//   [320,    480) : float  inv32[40]
//   [512,  16896) : uint flagbits[4096]  (16-bit mask per 16-row wave)
//   [32768,131072): ushort bhi[48][1024] (bf16 hi of mem*inv32, rows 40-47 = 0)
//   [131072,229376): ushort blo[48][1024] (bf16 lo)

#define DIM 1024
#define NMEM 40

typedef float  vf4 __attribute__((ext_vector_type(4)));
typedef float  f4a __attribute__((ext_vector_type(4)));
typedef short  s8v __attribute__((ext_vector_type(8)));

union FragU { s8v v; unsigned int u[4]; };

constexpr float TAU = 2.5e-4f;   // normalized top-2 gap below which f64 re-resolve

// ---------------- Kernel 1: memory-row inverse norms (f32 + f64) ----------------
__global__ __launch_bounds__(64) void k_norms(const float* __restrict__ mem,
                                              double* __restrict__ inv64,
                                              float* __restrict__ inv32) {
  const int m = blockIdx.x;      // 40 blocks, 1 wave each
  const int lane = threadIdx.x;
  const float* __restrict__ row = mem + (size_t)m * DIM;
  double s = 0.0;
#pragma unroll
  for (int i = 0; i < DIM / 64; ++i) {
    double v = (double)row[lane + 64 * i];
    s = fma(v, v, s);
  }
#pragma unroll
  for (int off = 32; off > 0; off >>= 1) s += __shfl_xor(s, off, 64);
  if (lane == 0) {
    double n = sqrt(s);
    n = (n > 1e-8) ? n : 1e-8;
    inv64[m] = 1.0 / n;
    inv32[m] = (float)(1.0 / n);
  }
}

// ---------------- Kernel 1b: split normalized memory into bf16 hi/lo ----------------
__global__ __launch_bounds__(256) void k_prep(const float* __restrict__ mem,
                                              const float* __restrict__ inv32,
                                              unsigned short* __restrict__ bhi,
                                              unsigned short* __restrict__ blo) {
  const int m = blockIdx.x;            // 0..47 (40 real + 8 zero-pad)
  const int k0 = threadIdx.x * 4;      // 1024/256 = 4 elems/thread
  if (m < NMEM) {
    const float s = inv32[m];
#pragma unroll
    for (int j = 0; j < 4; ++j) {
      float w = mem[(size_t)m * DIM + k0 + j] * s;
      unsigned int u = __builtin_bit_cast(unsigned int, w);
      bhi[(size_t)m * DIM + k0 + j] = (unsigned short)(u >> 16);
      float hf = __builtin_bit_cast(float, u & 0xFFFF0000u);
      float lo = w - hf;
      blo[(size_t)m * DIM + k0 + j] =
          (unsigned short)(__builtin_bit_cast(unsigned int, lo) >> 16);
    }
  } else {
#pragma unroll
    for (int j = 0; j < 4; ++j) {
      bhi[(size_t)m * DIM + k0 + j] = 0;
      blo[(size_t)m * DIM + k0 + j] = 0;
    }
  }
}

// ---------------- Kernel 2: MFMA sims + argmax + gather + x-copy ----------------
// Block = 256 thr = 4 independent waves (no barriers). Wave = 16 x-rows.
// A-frag (x): lane holds row (l&15), k-slice (l>>4)*8..+8 -> fully coalesced
// 128B lines. B-frag (mem): lane holds m-col (l&15)+16*tile, same k-slice.
// C layout (m89-verified): lane holds D[(l>>4)*4+j][(l&15)+16*tile].
__global__ __launch_bounds__(256, 4) void k_main(const float* __restrict__ x,
                                                 const float* __restrict__ mem,
                                                 const unsigned short* __restrict__ bhi,
                                                 const unsigned short* __restrict__ blo,
                                                 float* __restrict__ out_near,
                                                 float* __restrict__ out_x,
                                                 unsigned int* __restrict__ flagbits) {
  __shared__ float nxw[4][16];
  __shared__ int   amaxw[4][16];
  __shared__ int   flagw[4][16];

  const int tid  = threadIdx.x;
  const int lane = tid & 63;
  const int w    = __builtin_amdgcn_readfirstlane(tid >> 6);
  const int row  = lane & 15;          // x-row within wave tile / m-col within tile
  const int kg   = lane >> 4;          // k-subslice group (0..3)
  const int rowbase = blockIdx.x * 64 + w * 16;

  const float* __restrict__ xp  = x     + (size_t)(rowbase + row) * DIM + kg * 8;
  float* __restrict__ oxp       = out_x + (size_t)(rowbase + row) * DIM + kg * 8;
  const unsigned short* __restrict__ bp = bhi + (size_t)row * DIM + kg * 8;
  const unsigned short* __restrict__ lp = blo + (size_t)row * DIM + kg * 8;

  f4a acc[3];
#pragma unroll
  for (int t = 0; t < 3; ++t) acc[t] = (f4a){0.f, 0.f, 0.f, 0.f};
  float nx = 0.f;

  vf4 cA0, cA1, nA0, nA1;
  cA0 = *(const vf4*)(xp);
  cA1 = *(const vf4*)(xp + 4);

  auto step = [&](vf4& a0, vf4& a1, vf4& n0, vf4& n1, int t) {
    // B-frags for this K-step (L2-resident, distinct data per lane)
    s8v bh[3], bl[3];
#pragma unroll
    for (int tt = 0; tt < 3; ++tt) {
      bh[tt] = *(const s8v*)(bp + (size_t)tt * 16 * DIM + t * 32);
      bl[tt] = *(const s8v*)(lp + (size_t)tt * 16 * DIM + t * 32);
    }
    if (t < 31) {                       // A prefetch (HBM) into alternate regs
      n0 = *(const vf4*)(xp + (t + 1) * 32);
      n1 = *(const vf4*)(xp + (t + 1) * 32 + 4);
    }
    // x-copy from the same registers (x read exactly once). REGULAR stores:
    // L2 merges the per-row 32B pieces into full lines (R9's nt stores didn't).
    *(vf4*)(oxp + t * 32)     = a0;
    *(vf4*)(oxp + t * 32 + 4) = a1;
    // ||x||^2 partial
    nx = fmaf(a0.x, a0.x, fmaf(a0.y, a0.y, fmaf(a0.z, a0.z, fmaf(a0.w, a0.w, nx))));
    nx = fmaf(a1.x, a1.x, fmaf(a1.y, a1.y, fmaf(a1.z, a1.z, fmaf(a1.w, a1.w, nx))));
    // split f32 -> hi/lo bf16 (truncation; residual ~2^-17)
    FragU ah, al;
    {
      float f[8] = {a0.x, a0.y, a0.z, a0.w, a1.x, a1.y, a1.z, a1.w};
#pragma unroll
      for (int p = 0; p < 4; ++p) {
        unsigned int u0 = __builtin_bit_cast(unsigned int, f[2 * p]);
        unsigned int u1 = __builtin_bit_cast(unsigned int, f[2 * p + 1]);
        ah.u[p] = (u1 & 0xFFFF0000u) | (u0 >> 16);
        float h0 = __builtin_bit_cast(float, u0 & 0xFFFF0000u);
        float h1 = __builtin_bit_cast(float, u1 & 0xFFFF0000u);
        float l0 = f[2 * p] - h0;
        float l1 = f[2 * p + 1] - h1;
        al.u[p] = (__builtin_bit_cast(unsigned int, l1) & 0xFFFF0000u) |
                  (__builtin_bit_cast(unsigned int, l0) >> 16);
      }
    }
    // 4 split passes x 3 N-tiles
#pragma unroll
    for (int tt = 0; tt < 3; ++tt) {
      acc[tt] = __builtin_amdgcn_mfma_f32_16x16x32_bf16(ah.v, bh[tt], acc[tt], 0, 0, 0);
      acc[tt] = __builtin_amdgcn_mfma_f32_16x16x32_bf16(ah.v, bl[tt], acc[tt], 0, 0, 0);
      acc[tt] = __builtin_amdgcn_mfma_f32_16x16x32_bf16(al.v, bh[tt], acc[tt], 0, 0, 0);
      acc[tt] = __builtin_amdgcn_mfma_f32_16x16x32_bf16(al.v, bl[tt], acc[tt], 0, 0, 0);
    }
  };

  for (int t = 0; t < 32; t += 2) {     // explicit double-buffer, static indexing
    step(cA0, cA1, nA0, nA1, t);
    step(nA0, nA1, cA0, cA1, t + 1);
  }

  // ||x||^2: sum the 4 k-groups (lanes l, l^16, l^32, l^48 share row l&15)
  nx += __shfl_xor(nx, 16, 64);
  nx += __shfl_xor(nx, 32, 64);
  if (lane < 16) nxw[w][lane] = nx;

  // per-lane top-2: lane holds sims for rows (l>>4)*4+j, m-cols (l&15)+16t
  float v1[4], v2[4];
  int   i1[4];
#pragma unroll
  for (int j = 0; j < 4; ++j) {
    float c0 = acc[0][j], c1 = acc[1][j];
    float c2 = (row < 8) ? acc[2][j] : -3.4e38f;   // cols 40-47 are pad
    float a1 = c0, a2 = -3.4e38f;
    int   ai = row;
    if (c1 > a1) { a2 = a1; a1 = c1; ai = row + 16; } else a2 = c1;
    if (c2 > a1) { a2 = a1; a1 = c2; ai = row + 32; } else if (c2 > a2) a2 = c2;
    v1[j] = a1; v2[j] = a2; i1[j] = ai;
  }
#pragma unroll
  for (int st = 1; st < 16; st <<= 1) {  // reduce over the 16 lanes of each row-group
#pragma unroll
    for (int j = 0; j < 4; ++j) {
      float o1 = __shfl_xor(v1[j], st, 64);
      float o2 = __shfl_xor(v2[j], st, 64);
      int   oi = __shfl_xor(i1[j], st, 64);
      if (o1 > v1[j]) { v2[j] = fmaxf(v1[j], o2); v1[j] = o1; i1[j] = oi; }
      else            { v2[j] = fmaxf(v2[j], o1); }           // tie -> gap 0 -> flagged
    }
  }
  if ((lane & 15) == 0) {
    const int g = lane >> 4;
#pragma unroll
    for (int j = 0; j < 4; ++j) {
      const int r = 4 * g + j;
      float gap = (v1[j] - v2[j]) * rsqrtf(fmaxf(nxw[w][r], 1e-30f));
      flagw[w][r] = !(gap >= TAU);     // NaN-safe
      amaxw[w][r] = i1[j];
    }
  }
  int flv = flagw[w][lane & 15];
  unsigned long long bmask = __ballot(flv != 0);
  if (lane == 0) flagbits[blockIdx.x * 4 + w] = (unsigned int)(bmask & 0xFFFFull);

  // gather-copy memory[amax] -> out_near (16 rows/wave, coalesced; nt OK:
  // 64 lanes x 16B contiguous = full lines per instruction)
  const vf4* __restrict__ m4 = (const vf4*)mem;
#pragma unroll 1
  for (int r = 0; r < 16; ++r) {
    int am = __builtin_amdgcn_readfirstlane(amaxw[w][r]);
    const vf4* __restrict__ src = m4 + (size_t)am * (DIM / 4);
    vf4* __restrict__ dst = (vf4*)out_near + (size_t)(rowbase + r) * (DIM / 4);
#pragma unroll
    for (int j = 0; j < 4; ++j) {
      vf4 v = src[lane + 64 * j];
      __builtin_nontemporal_store(v, &dst[lane + 64 * j]);
    }
  }
}

// ---------------- Kernel 3: f64 re-resolution of razor-thin rows ----------------
__global__ __launch_bounds__(256) void k_refine(const float* __restrict__ x,
                                                const float* __restrict__ mem,
                                                const double* __restrict__ inv64,
                                                const unsigned int* __restrict__ flagbits,
                                                float* __restrict__ out_near) {
  unsigned int mask = flagbits[blockIdx.x];
  if (mask == 0u) return;                   // uniform; nearly all blocks exit
  const int tid = threadIdx.x;
  const int lane = tid & 63;
  const int wid = tid >> 6;
  __shared__ double bval[4];
  __shared__ int bidx[4];
  while (mask) {
    int r = __ffs(mask) - 1;
    mask &= (mask - 1u);
    int rrow = blockIdx.x * 16 + r;
    const float* __restrict__ xr = x + (size_t)rrow * DIM;
    double xd[16];
#pragma unroll
    for (int i = 0; i < 16; ++i) xd[i] = (double)xr[lane + 64 * i];
    double best = -1e300;
    int bi = 0;
    for (int q = 0; q < 10; ++q) {
      int m = wid * 10 + q;
      const float* __restrict__ mr = mem + (size_t)m * DIM;
      double s = 0.0;
#pragma unroll
      for (int i = 0; i < 16; ++i) s = fma(xd[i], (double)mr[lane + 64 * i], s);
#pragma unroll
      for (int off = 32; off > 0; off >>= 1) s += __shfl_xor(s, off, 64);
      double v = s * inv64[m];              // identical (bitwise) across lanes
      if (v > best) { best = v; bi = m; }   // strict > keeps lowest m on ties
    }
    if (lane == 0) { bval[wid] = best; bidx[wid] = bi; }
    __syncthreads();
    double g = bval[0];
    int gi = bidx[0];
#pragma unroll
    for (int gg = 1; gg < 4; ++gg) {
      if (bval[gg] > g) { g = bval[gg]; gi = bidx[gg]; }
    }
    const float4* __restrict__ src = (const float4*)mem + (size_t)gi * (DIM / 4);
    float4* __restrict__ dst = (float4*)out_near + (size_t)rrow * (DIM / 4);
    dst[tid] = src[tid];                    // 256 x 16B = full row, coalesced
    __syncthreads();                        // LDS reuse guard for next flagged row
  }
}

extern "C" void kernel_launch(void* const* d_in, const int* in_sizes, int n_in,
                              void* d_out, int out_size, void* d_ws, size_t ws_size,
                              hipStream_t stream) {
  const float* x   = (const float*)d_in[0];
  const float* mem = (const float*)d_in[1];
  // d_in[2] = top_k (unused: reference only consumes idx[:,0], i.e. the argmax)

  const int n_rows = in_sizes[0] / DIM;          // 65536
  float* out_near = (float*)d_out;
  float* out_x    = (float*)d_out + (size_t)n_rows * DIM;

  double* inv64 = (double*)d_ws;
  float*  inv32 = (float*)((char*)d_ws + 320);
  unsigned int* flagbits = (unsigned int*)((char*)d_ws + 512);
  unsigned short* bhi = (unsigned short*)((char*)d_ws + 32768);
  unsigned short* blo = (unsigned short*)((char*)d_ws + 131072);

  hipLaunchKernelGGL(k_norms, dim3(NMEM), dim3(64), 0, stream, mem, inv64, inv32);
  hipLaunchKernelGGL(k_prep,  dim3(48),   dim3(256), 0, stream, mem, inv32, bhi, blo);
  hipLaunchKernelGGL(k_main,  dim3(n_rows / 64), dim3(256), 0, stream,
                     x, mem, bhi, blo, out_near, out_x, flagbits);
  hipLaunchKernelGGL(k_refine, dim3(n_rows / 16), dim3(256), 0, stream,
                     x, mem, inv64, flagbits, out_near);
}

// Round 12
// 281.621 us; speedup vs baseline: 1.1803x; 1.0847x over previous
//
#include <hip/hip_runtime.h>

// Problem: nearest = memory[argmax_m cosine(x_row, memory_m)], plus copy of x.
//   x: 65536 x 1024 f32, memory: 40 x 1024 f32, out = [nearest | x-copy]
//
// R12 = R9 (MFMA split-f32, nt stores, validated absmax=0, best at 260us)
// + ONE change: A(x) prefetch deepened 1 -> 4 steps via 4 NAMED register
// slots (static indexing only; R10's array/lambda variant caused scratch).
// Load->use distance now ~4 steps (~600-800cy) >= L3/HBM latency, so the
// per-step A-wait (~300-500cy, the ~2x-over-floor gap) disappears.
// R11 (regular x-copy stores) regressed 260->305: nt stores kept. B-frags
// stay single-buffered (L1/L2-resident, latency covered by in-step work).
//
// d_ws layout (bytes):
//   [0,      320) : double inv64[40]
//   [320,    480) : float  inv32[40]
//   [512,  16896) : uint flagbits[4096]  (16-bit mask per 16-row wave)
//   [32768,131072): ushort bhi[48][1024] (bf16 hi of mem*inv32, rows 40-47 = 0)
//   [131072,229376): ushort blo[48][1024] (bf16 lo)

#define DIM 1024
#define NMEM 40

typedef float  vf4 __attribute__((ext_vector_type(4)));
typedef float  f4a __attribute__((ext_vector_type(4)));
typedef short  s8v __attribute__((ext_vector_type(8)));

union FragU { s8v v; unsigned int u[4]; };

constexpr float TAU = 2.5e-4f;   // normalized top-2 gap below which f64 re-resolve

// ---------------- Kernel 1: memory-row inverse norms (f32 + f64) ----------------
__global__ __launch_bounds__(64) void k_norms(const float* __restrict__ mem,
                                              double* __restrict__ inv64,
                                              float* __restrict__ inv32) {
  const int m = blockIdx.x;      // 40 blocks, 1 wave each
  const int lane = threadIdx.x;
  const float* __restrict__ row = mem + (size_t)m * DIM;
  double s = 0.0;
#pragma unroll
  for (int i = 0; i < DIM / 64; ++i) {
    double v = (double)row[lane + 64 * i];
    s = fma(v, v, s);
  }
#pragma unroll
  for (int off = 32; off > 0; off >>= 1) s += __shfl_xor(s, off, 64);
  if (lane == 0) {
    double n = sqrt(s);
    n = (n > 1e-8) ? n : 1e-8;
    inv64[m] = 1.0 / n;
    inv32[m] = (float)(1.0 / n);
  }
}

// ---------------- Kernel 1b: split normalized memory into bf16 hi/lo ----------------
__global__ __launch_bounds__(256) void k_prep(const float* __restrict__ mem,
                                              const float* __restrict__ inv32,
                                              unsigned short* __restrict__ bhi,
                                              unsigned short* __restrict__ blo) {
  const int m = blockIdx.x;            // 0..47 (40 real + 8 zero-pad)
  const int k0 = threadIdx.x * 4;      // 1024/256 = 4 elems/thread
  if (m < NMEM) {
    const float s = inv32[m];
#pragma unroll
    for (int j = 0; j < 4; ++j) {
      float w = mem[(size_t)m * DIM + k0 + j] * s;
      unsigned int u = __builtin_bit_cast(unsigned int, w);
      bhi[(size_t)m * DIM + k0 + j] = (unsigned short)(u >> 16);
      float hf = __builtin_bit_cast(float, u & 0xFFFF0000u);
      float lo = w - hf;
      blo[(size_t)m * DIM + k0 + j] =
          (unsigned short)(__builtin_bit_cast(unsigned int, lo) >> 16);
    }
  } else {
#pragma unroll
    for (int j = 0; j < 4; ++j) {
      bhi[(size_t)m * DIM + k0 + j] = 0;
      blo[(size_t)m * DIM + k0 + j] = 0;
    }
  }
}

// ---------------- Kernel 2: MFMA sims + argmax + gather + x-copy ----------------
// Block = 256 thr = 4 independent waves (no barriers). Wave = 16 x-rows.
// A-frag (x): lane holds row (l&15), k-slice (l>>4)*8..+8 -> fully coalesced
// 128B lines. B-frag (mem): lane holds m-col (l&15)+16*tile, same k-slice.
// C layout (m89-verified): lane holds D[(l>>4)*4+j][(l&15)+16*tile].
__global__ __launch_bounds__(256, 4) void k_main(const float* __restrict__ x,
                                                 const float* __restrict__ mem,
                                                 const unsigned short* __restrict__ bhi,
                                                 const unsigned short* __restrict__ blo,
                                                 float* __restrict__ out_near,
                                                 float* __restrict__ out_x,
                                                 unsigned int* __restrict__ flagbits) {
  __shared__ float nxw[4][16];
  __shared__ int   amaxw[4][16];
  __shared__ int   flagw[4][16];

  const int tid  = threadIdx.x;
  const int lane = tid & 63;
  const int w    = __builtin_amdgcn_readfirstlane(tid >> 6);
  const int row  = lane & 15;          // x-row within wave tile / m-col within tile
  const int kg   = lane >> 4;          // k-subslice group (0..3)
  const int rowbase = blockIdx.x * 64 + w * 16;

  const float* __restrict__ xp  = x     + (size_t)(rowbase + row) * DIM + kg * 8;
  float* __restrict__ oxp       = out_x + (size_t)(rowbase + row) * DIM + kg * 8;
  const unsigned short* __restrict__ bp = bhi + (size_t)row * DIM + kg * 8;
  const unsigned short* __restrict__ lp = blo + (size_t)row * DIM + kg * 8;

  f4a acc[3];
#pragma unroll
  for (int t = 0; t < 3; ++t) acc[t] = (f4a){0.f, 0.f, 0.f, 0.f};
  float nx = 0.f;

  // ---- 4-deep A prefetch ring: NAMED slots only (no runtime indexing) ----
  vf4 S0a, S0b, S1a, S1b, S2a, S2b, S3a, S3b;
  S0a = *(const vf4*)(xp + 0 * 32);  S0b = *(const vf4*)(xp + 0 * 32 + 4);
  S1a = *(const vf4*)(xp + 1 * 32);  S1b = *(const vf4*)(xp + 1 * 32 + 4);
  S2a = *(const vf4*)(xp + 2 * 32);  S2b = *(const vf4*)(xp + 2 * 32 + 4);
  S3a = *(const vf4*)(xp + 3 * 32);  S3b = *(const vf4*)(xp + 3 * 32 + 4);

  // STEP(T, Sa, Sb, PF): consume slot (Sa,Sb) for K-step T; if PF, refill the
  // slot with step T+4's data immediately after the register copy.
#define STEP(T, Sa, Sb, PF)                                                     \
  {                                                                             \
    vf4 a0 = Sa, a1 = Sb;                                                       \
    if (PF) {                                                                   \
      Sa = *(const vf4*)(xp + ((T) + 4) * 32);                                  \
      Sb = *(const vf4*)(xp + ((T) + 4) * 32 + 4);                              \
    }                                                                           \
    s8v bh[3], bl[3];                                                           \
    _Pragma("unroll")                                                           \
    for (int tt = 0; tt < 3; ++tt) {                                            \
      bh[tt] = *(const s8v*)(bp + (size_t)tt * 16 * DIM + (T) * 32);            \
      bl[tt] = *(const s8v*)(lp + (size_t)tt * 16 * DIM + (T) * 32);            \
    }                                                                           \
    __builtin_nontemporal_store(a0, (vf4*)(oxp + (T) * 32));                    \
    __builtin_nontemporal_store(a1, (vf4*)(oxp + (T) * 32 + 4));                \
    nx = fmaf(a0.x, a0.x, fmaf(a0.y, a0.y, fmaf(a0.z, a0.z, fmaf(a0.w, a0.w, nx)))); \
    nx = fmaf(a1.x, a1.x, fmaf(a1.y, a1.y, fmaf(a1.z, a1.z, fmaf(a1.w, a1.w, nx)))); \
    FragU ah, al;                                                               \
    {                                                                           \
      float f[8] = {a0.x, a0.y, a0.z, a0.w, a1.x, a1.y, a1.z, a1.w};            \
      _Pragma("unroll")                                                         \
      for (int p = 0; p < 4; ++p) {                                             \
        unsigned int u0 = __builtin_bit_cast(unsigned int, f[2 * p]);           \
        unsigned int u1 = __builtin_bit_cast(unsigned int, f[2 * p + 1]);       \
        ah.u[p] = (u1 & 0xFFFF0000u) | (u0 >> 16);                              \
        float h0 = __builtin_bit_cast(float, u0 & 0xFFFF0000u);                 \
        float h1 = __builtin_bit_cast(float, u1 & 0xFFFF0000u);                 \
        float l0 = f[2 * p] - h0;                                               \
        float l1 = f[2 * p + 1] - h1;                                           \
        al.u[p] = (__builtin_bit_cast(unsigned int, l1) & 0xFFFF0000u) |        \
                  (__builtin_bit_cast(unsigned int, l0) >> 16);                 \
      }                                                                         \
    }                                                                           \
    _Pragma("unroll")                                                           \
    for (int tt = 0; tt < 3; ++tt) {                                            \
      acc[tt] = __builtin_amdgcn_mfma_f32_16x16x32_bf16(ah.v, bh[tt], acc[tt], 0, 0, 0); \
      acc[tt] = __builtin_amdgcn_mfma_f32_16x16x32_bf16(ah.v, bl[tt], acc[tt], 0, 0, 0); \
      acc[tt] = __builtin_amdgcn_mfma_f32_16x16x32_bf16(al.v, bh[tt], acc[tt], 0, 0, 0); \
      acc[tt] = __builtin_amdgcn_mfma_f32_16x16x32_bf16(al.v, bl[tt], acc[tt], 0, 0, 0); \
    }                                                                           \
  }

#pragma unroll 1
  for (int t = 0; t < 24; t += 4) {    // steady state: prefetch always legal (t+7+4 <= 31... t<=24)
    STEP(t + 0, S0a, S0b, true)
    STEP(t + 1, S1a, S1b, true)
    STEP(t + 2, S2a, S2b, true)
    STEP(t + 3, S3a, S3b, true)
  }
  // tail: t = 24..27 prefetch only while T+4 < 32; t = 28..31 no prefetch
  STEP(24, S0a, S0b, true)             // loads 28
  STEP(25, S1a, S1b, true)             // loads 29
  STEP(26, S2a, S2b, true)             // loads 30
  STEP(27, S3a, S3b, true)             // loads 31
  STEP(28, S0a, S0b, false)
  STEP(29, S1a, S1b, false)
  STEP(30, S2a, S2b, false)
  STEP(31, S3a, S3b, false)
#undef STEP

  // ||x||^2: sum the 4 k-groups (lanes l, l^16, l^32, l^48 share row l&15)
  nx += __shfl_xor(nx, 16, 64);
  nx += __shfl_xor(nx, 32, 64);
  if (lane < 16) nxw[w][lane] = nx;

  // per-lane top-2: lane holds sims for rows (l>>4)*4+j, m-cols (l&15)+16t
  float v1[4], v2[4];
  int   i1[4];
#pragma unroll
  for (int j = 0; j < 4; ++j) {
    float c0 = acc[0][j], c1 = acc[1][j];
    float c2 = (row < 8) ? acc[2][j] : -3.4e38f;   // cols 40-47 are pad
    float a1 = c0, a2 = -3.4e38f;
    int   ai = row;
    if (c1 > a1) { a2 = a1; a1 = c1; ai = row + 16; } else a2 = c1;
    if (c2 > a1) { a2 = a1; a1 = c2; ai = row + 32; } else if (c2 > a2) a2 = c2;
    v1[j] = a1; v2[j] = a2; i1[j] = ai;
  }
#pragma unroll
  for (int st = 1; st < 16; st <<= 1) {  // reduce over the 16 lanes of each row-group
#pragma unroll
    for (int j = 0; j < 4; ++j) {
      float o1 = __shfl_xor(v1[j], st, 64);
      float o2 = __shfl_xor(v2[j], st, 64);
      int   oi = __shfl_xor(i1[j], st, 64);
      if (o1 > v1[j]) { v2[j] = fmaxf(v1[j], o2); v1[j] = o1; i1[j] = oi; }
      else            { v2[j] = fmaxf(v2[j], o1); }           // tie -> gap 0 -> flagged
    }
  }
  if ((lane & 15) == 0) {
    const int g = lane >> 4;
#pragma unroll
    for (int j = 0; j < 4; ++j) {
      const int r = 4 * g + j;
      float gap = (v1[j] - v2[j]) * rsqrtf(fmaxf(nxw[w][r], 1e-30f));
      flagw[w][r] = !(gap >= TAU);     // NaN-safe
      amaxw[w][r] = i1[j];
    }
  }
  int flv = flagw[w][lane & 15];
  unsigned long long bmask = __ballot(flv != 0);
  if (lane == 0) flagbits[blockIdx.x * 4 + w] = (unsigned int)(bmask & 0xFFFFull);

  // gather-copy memory[amax] -> out_near (16 rows/wave, coalesced; nt OK:
  // 64 lanes x 16B contiguous = full lines per instruction)
  const vf4* __restrict__ m4 = (const vf4*)mem;
#pragma unroll 1
  for (int r = 0; r < 16; ++r) {
    int am = __builtin_amdgcn_readfirstlane(amaxw[w][r]);
    const vf4* __restrict__ src = m4 + (size_t)am * (DIM / 4);
    vf4* __restrict__ dst = (vf4*)out_near + (size_t)(rowbase + r) * (DIM / 4);
#pragma unroll
    for (int j = 0; j < 4; ++j) {
      vf4 v = src[lane + 64 * j];
      __builtin_nontemporal_store(v, &dst[lane + 64 * j]);
    }
  }
}

// ---------------- Kernel 3: f64 re-resolution of razor-thin rows ----------------
__global__ __launch_bounds__(256) void k_refine(const float* __restrict__ x,
                                                const float* __restrict__ mem,
                                                const double* __restrict__ inv64,
                                                const unsigned int* __restrict__ flagbits,
                                                float* __restrict__ out_near) {
  unsigned int mask = flagbits[blockIdx.x];
  if (mask == 0u) return;                   // uniform; nearly all blocks exit
  const int tid = threadIdx.x;
  const int lane = tid & 63;
  const int wid = tid >> 6;
  __shared__ double bval[4];
  __shared__ int bidx[4];
  while (mask) {
    int r = __ffs(mask) - 1;
    mask &= (mask - 1u);
    int rrow = blockIdx.x * 16 + r;
    const float* __restrict__ xr = x + (size_t)rrow * DIM;
    double xd[16];
#pragma unroll
    for (int i = 0; i < 16; ++i) xd[i] = (double)xr[lane + 64 * i];
    double best = -1e300;
    int bi = 0;
    for (int q = 0; q < 10; ++q) {
      int m = wid * 10 + q;
      const float* __restrict__ mr = mem + (size_t)m * DIM;
      double s = 0.0;
#pragma unroll
      for (int i = 0; i < 16; ++i) s = fma(xd[i], (double)mr[lane + 64 * i], s);
#pragma unroll
      for (int off = 32; off > 0; off >>= 1) s += __shfl_xor(s, off, 64);
      double v = s * inv64[m];              // identical (bitwise) across lanes
      if (v > best) { best = v; bi = m; }   // strict > keeps lowest m on ties
    }
    if (lane == 0) { bval[wid] = best; bidx[wid] = bi; }
    __syncthreads();
    double g = bval[0];
    int gi = bidx[0];
#pragma unroll
    for (int gg = 1; gg < 4; ++gg) {
      if (bval[gg] > g) { g = bval[gg]; gi = bidx[gg]; }
    }
    const float4* __restrict__ src = (const float4*)mem + (size_t)gi * (DIM / 4);
    float4* __restrict__ dst = (float4*)out_near + (size_t)rrow * (DIM / 4);
    dst[tid] = src[tid];                    // 256 x 16B = full row, coalesced
    __syncthreads();                        // LDS reuse guard for next flagged row
  }
}

extern "C" void kernel_launch(void* const* d_in, const int* in_sizes, int n_in,
                              void* d_out, int out_size, void* d_ws, size_t ws_size,
                              hipStream_t stream) {
  const float* x   = (const float*)d_in[0];
  const float* mem = (const float*)d_in[1];
  // d_in[2] = top_k (unused: reference only consumes idx[:,0], i.e. the argmax)

  const int n_rows = in_sizes[0] / DIM;          // 65536
  float* out_near = (float*)d_out;
  float* out_x    = (float*)d_out + (size_t)n_rows * DIM;

  double* inv64 = (double*)d_ws;
  float*  inv32 = (float*)((char*)d_ws + 320);
  unsigned int* flagbits = (unsigned int*)((char*)d_ws + 512);
  unsigned short* bhi = (unsigned short*)((char*)d_ws + 32768);
  unsigned short* blo = (unsigned short*)((char*)d_ws + 131072);

  hipLaunchKernelGGL(k_norms, dim3(NMEM), dim3(64), 0, stream, mem, inv64, inv32);
  hipLaunchKernelGGL(k_prep,  dim3(48),   dim3(256), 0, stream, mem, inv32, bhi, blo);
  hipLaunchKernelGGL(k_main,  dim3(n_rows / 64), dim3(256), 0, stream,
                     x, mem, bhi, blo, out_near, out_x, flagbits);
  hipLaunchKernelGGL(k_refine, dim3(n_rows / 16), dim3(256), 0, stream,
                     x, mem, inv64, flagbits, out_near);
}

// Round 13
// 272.678 us; speedup vs baseline: 1.2190x; 1.0328x over previous
//
#include <hip/hip_runtime.h>

// Problem: nearest = memory[argmax_m cosine(x_row, memory_m)], plus copy of x.
//   x: 65536 x 1024 f32, memory: 40 x 1024 f32, out = [nearest | x-copy]
//
// R13 = R12 (4-deep named-slot A prefetch) with the VMEM ISSUE ORDER fixed:
// per step, B-loads are issued FIRST, then the A-refill (t+4), then the nt
// stores. vmcnt retires IN ISSUE ORDER, so the pre-MFMA wait for B becomes
// vmcnt<=4 (A+stores newer, stay outstanding) instead of R12's vmcnt<=2 which
// forced the t+4 A-load (full HBM latency) to drain EVERY step. A-consume
// at step t now tolerates ~14 outstanding ops -> 4-step (~1200cy) load->use
// distance >= HBM latency -> steady state never stalls on x.
// R9=260us (1-deep, B-first), R12=282us (4-deep, A-first): order is the lever.
//
// d_ws layout (bytes):
//   [0,      320) : double inv64[40]
//   [320,    480) : float  inv32[40]
//   [512,  16896) : uint flagbits[4096]  (16-bit mask per 16-row wave)
//   [32768,131072): ushort bhi[48][1024] (bf16 hi of mem*inv32, rows 40-47 = 0)
//   [131072,229376): ushort blo[48][1024] (bf16 lo)

#define DIM 1024
#define NMEM 40

typedef float  vf4 __attribute__((ext_vector_type(4)));
typedef float  f4a __attribute__((ext_vector_type(4)));
typedef short  s8v __attribute__((ext_vector_type(8)));

union FragU { s8v v; unsigned int u[4]; };

constexpr float TAU = 2.5e-4f;   // normalized top-2 gap below which f64 re-resolve

// ---------------- Kernel 1: memory-row inverse norms (f32 + f64) ----------------
__global__ __launch_bounds__(64) void k_norms(const float* __restrict__ mem,
                                              double* __restrict__ inv64,
                                              float* __restrict__ inv32) {
  const int m = blockIdx.x;      // 40 blocks, 1 wave each
  const int lane = threadIdx.x;
  const float* __restrict__ row = mem + (size_t)m * DIM;
  double s = 0.0;
#pragma unroll
  for (int i = 0; i < DIM / 64; ++i) {
    double v = (double)row[lane + 64 * i];
    s = fma(v, v, s);
  }
#pragma unroll
  for (int off = 32; off > 0; off >>= 1) s += __shfl_xor(s, off, 64);
  if (lane == 0) {
    double n = sqrt(s);
    n = (n > 1e-8) ? n : 1e-8;
    inv64[m] = 1.0 / n;
    inv32[m] = (float)(1.0 / n);
  }
}

// ---------------- Kernel 1b: split normalized memory into bf16 hi/lo ----------------
__global__ __launch_bounds__(256) void k_prep(const float* __restrict__ mem,
                                              const float* __restrict__ inv32,
                                              unsigned short* __restrict__ bhi,
                                              unsigned short* __restrict__ blo) {
  const int m = blockIdx.x;            // 0..47 (40 real + 8 zero-pad)
  const int k0 = threadIdx.x * 4;      // 1024/256 = 4 elems/thread
  if (m < NMEM) {
    const float s = inv32[m];
#pragma unroll
    for (int j = 0; j < 4; ++j) {
      float w = mem[(size_t)m * DIM + k0 + j] * s;
      unsigned int u = __builtin_bit_cast(unsigned int, w);
      bhi[(size_t)m * DIM + k0 + j] = (unsigned short)(u >> 16);
      float hf = __builtin_bit_cast(float, u & 0xFFFF0000u);
      float lo = w - hf;
      blo[(size_t)m * DIM + k0 + j] =
          (unsigned short)(__builtin_bit_cast(unsigned int, lo) >> 16);
    }
  } else {
#pragma unroll
    for (int j = 0; j < 4; ++j) {
      bhi[(size_t)m * DIM + k0 + j] = 0;
      blo[(size_t)m * DIM + k0 + j] = 0;
    }
  }
}

// ---------------- Kernel 2: MFMA sims + argmax + gather + x-copy ----------------
// Block = 256 thr = 4 independent waves (no barriers). Wave = 16 x-rows.
// A-frag (x): lane holds row (l&15), k-slice (l>>4)*8..+8 -> fully coalesced
// 128B lines. B-frag (mem): lane holds m-col (l&15)+16*tile, same k-slice.
// C layout (m89-verified): lane holds D[(l>>4)*4+j][(l&15)+16*tile].
__global__ __launch_bounds__(256, 4) void k_main(const float* __restrict__ x,
                                                 const float* __restrict__ mem,
                                                 const unsigned short* __restrict__ bhi,
                                                 const unsigned short* __restrict__ blo,
                                                 float* __restrict__ out_near,
                                                 float* __restrict__ out_x,
                                                 unsigned int* __restrict__ flagbits) {
  __shared__ float nxw[4][16];
  __shared__ int   amaxw[4][16];
  __shared__ int   flagw[4][16];

  const int tid  = threadIdx.x;
  const int lane = tid & 63;
  const int w    = __builtin_amdgcn_readfirstlane(tid >> 6);
  const int row  = lane & 15;          // x-row within wave tile / m-col within tile
  const int kg   = lane >> 4;          // k-subslice group (0..3)
  const int rowbase = blockIdx.x * 64 + w * 16;

  const float* __restrict__ xp  = x     + (size_t)(rowbase + row) * DIM + kg * 8;
  float* __restrict__ oxp       = out_x + (size_t)(rowbase + row) * DIM + kg * 8;
  const unsigned short* __restrict__ bp = bhi + (size_t)row * DIM + kg * 8;
  const unsigned short* __restrict__ lp = blo + (size_t)row * DIM + kg * 8;

  f4a acc[3];
#pragma unroll
  for (int t = 0; t < 3; ++t) acc[t] = (f4a){0.f, 0.f, 0.f, 0.f};
  float nx = 0.f;

  // ---- 4-deep A prefetch ring: NAMED slots only (no runtime indexing) ----
  vf4 S0a, S0b, S1a, S1b, S2a, S2b, S3a, S3b;
  S0a = *(const vf4*)(xp + 0 * 32);  S0b = *(const vf4*)(xp + 0 * 32 + 4);
  S1a = *(const vf4*)(xp + 1 * 32);  S1b = *(const vf4*)(xp + 1 * 32 + 4);
  S2a = *(const vf4*)(xp + 2 * 32);  S2b = *(const vf4*)(xp + 2 * 32 + 4);
  S3a = *(const vf4*)(xp + 3 * 32);  S3b = *(const vf4*)(xp + 3 * 32 + 4);

  // STEP(T, Sa, Sb, PF): K-step T. ISSUE ORDER: B-loads -> A-refill -> stores.
#define STEP(T, Sa, Sb, PF)                                                     \
  {                                                                             \
    s8v bh[3], bl[3];                                                           \
    _Pragma("unroll")                                                           \
    for (int tt = 0; tt < 3; ++tt) {                                            \
      bh[tt] = *(const s8v*)(bp + (size_t)tt * 16 * DIM + (T) * 32);            \
      bl[tt] = *(const s8v*)(lp + (size_t)tt * 16 * DIM + (T) * 32);            \
    }                                                                           \
    vf4 a0 = Sa, a1 = Sb;                                                       \
    if (PF) {                                                                   \
      Sa = *(const vf4*)(xp + ((T) + 4) * 32);                                  \
      Sb = *(const vf4*)(xp + ((T) + 4) * 32 + 4);                              \
    }                                                                           \
    __builtin_nontemporal_store(a0, (vf4*)(oxp + (T) * 32));                    \
    __builtin_nontemporal_store(a1, (vf4*)(oxp + (T) * 32 + 4));                \
    nx = fmaf(a0.x, a0.x, fmaf(a0.y, a0.y, fmaf(a0.z, a0.z, fmaf(a0.w, a0.w, nx)))); \
    nx = fmaf(a1.x, a1.x, fmaf(a1.y, a1.y, fmaf(a1.z, a1.z, fmaf(a1.w, a1.w, nx)))); \
    FragU ah, al;                                                               \
    {                                                                           \
      float f[8] = {a0.x, a0.y, a0.z, a0.w, a1.x, a1.y, a1.z, a1.w};            \
      _Pragma("unroll")                                                         \
      for (int p = 0; p < 4; ++p) {                                             \
        unsigned int u0 = __builtin_bit_cast(unsigned int, f[2 * p]);           \
        unsigned int u1 = __builtin_bit_cast(unsigned int, f[2 * p + 1]);       \
        ah.u[p] = (u1 & 0xFFFF0000u) | (u0 >> 16);                              \
        float h0 = __builtin_bit_cast(float, u0 & 0xFFFF0000u);                 \
        float h1 = __builtin_bit_cast(float, u1 & 0xFFFF0000u);                 \
        float l0 = f[2 * p] - h0;                                               \
        float l1 = f[2 * p + 1] - h1;                                           \
        al.u[p] = (__builtin_bit_cast(unsigned int, l1) & 0xFFFF0000u) |        \
                  (__builtin_bit_cast(unsigned int, l0) >> 16);                 \
      }                                                                         \
    }                                                                           \
    _Pragma("unroll")                                                           \
    for (int tt = 0; tt < 3; ++tt) {                                            \
      acc[tt] = __builtin_amdgcn_mfma_f32_16x16x32_bf16(ah.v, bh[tt], acc[tt], 0, 0, 0); \
      acc[tt] = __builtin_amdgcn_mfma_f32_16x16x32_bf16(ah.v, bl[tt], acc[tt], 0, 0, 0); \
      acc[tt] = __builtin_amdgcn_mfma_f32_16x16x32_bf16(al.v, bh[tt], acc[tt], 0, 0, 0); \
      acc[tt] = __builtin_amdgcn_mfma_f32_16x16x32_bf16(al.v, bl[tt], acc[tt], 0, 0, 0); \
    }                                                                           \
  }

#pragma unroll 1
  for (int t = 0; t < 24; t += 4) {    // steady state
    STEP(t + 0, S0a, S0b, true)
    STEP(t + 1, S1a, S1b, true)
    STEP(t + 2, S2a, S2b, true)
    STEP(t + 3, S3a, S3b, true)
  }
  STEP(24, S0a, S0b, true)             // loads 28
  STEP(25, S1a, S1b, true)             // loads 29
  STEP(26, S2a, S2b, true)             // loads 30
  STEP(27, S3a, S3b, true)             // loads 31
  STEP(28, S0a, S0b, false)
  STEP(29, S1a, S1b, false)
  STEP(30, S2a, S2b, false)
  STEP(31, S3a, S3b, false)
#undef STEP

  // ||x||^2: sum the 4 k-groups (lanes l, l^16, l^32, l^48 share row l&15)
  nx += __shfl_xor(nx, 16, 64);
  nx += __shfl_xor(nx, 32, 64);
  if (lane < 16) nxw[w][lane] = nx;

  // per-lane top-2: lane holds sims for rows (l>>4)*4+j, m-cols (l&15)+16t
  float v1[4], v2[4];
  int   i1[4];
#pragma unroll
  for (int j = 0; j < 4; ++j) {
    float c0 = acc[0][j], c1 = acc[1][j];
    float c2 = (row < 8) ? acc[2][j] : -3.4e38f;   // cols 40-47 are pad
    float a1 = c0, a2 = -3.4e38f;
    int   ai = row;
    if (c1 > a1) { a2 = a1; a1 = c1; ai = row + 16; } else a2 = c1;
    if (c2 > a1) { a2 = a1; a1 = c2; ai = row + 32; } else if (c2 > a2) a2 = c2;
    v1[j] = a1; v2[j] = a2; i1[j] = ai;
  }
#pragma unroll
  for (int st = 1; st < 16; st <<= 1) {  // reduce over the 16 lanes of each row-group
#pragma unroll
    for (int j = 0; j < 4; ++j) {
      float o1 = __shfl_xor(v1[j], st, 64);
      float o2 = __shfl_xor(v2[j], st, 64);
      int   oi = __shfl_xor(i1[j], st, 64);
      if (o1 > v1[j]) { v2[j] = fmaxf(v1[j], o2); v1[j] = o1; i1[j] = oi; }
      else            { v2[j] = fmaxf(v2[j], o1); }           // tie -> gap 0 -> flagged
    }
  }
  if ((lane & 15) == 0) {
    const int g = lane >> 4;
#pragma unroll
    for (int j = 0; j < 4; ++j) {
      const int r = 4 * g + j;
      float gap = (v1[j] - v2[j]) * rsqrtf(fmaxf(nxw[w][r], 1e-30f));
      flagw[w][r] = !(gap >= TAU);     // NaN-safe
      amaxw[w][r] = i1[j];
    }
  }
  int flv = flagw[w][lane & 15];
  unsigned long long bmask = __ballot(flv != 0);
  if (lane == 0) flagbits[blockIdx.x * 4 + w] = (unsigned int)(bmask & 0xFFFFull);

  // gather-copy memory[amax] -> out_near (16 rows/wave, coalesced; nt OK:
  // 64 lanes x 16B contiguous = full lines per instruction)
  const vf4* __restrict__ m4 = (const vf4*)mem;
#pragma unroll 1
  for (int r = 0; r < 16; ++r) {
    int am = __builtin_amdgcn_readfirstlane(amaxw[w][r]);
    const vf4* __restrict__ src = m4 + (size_t)am * (DIM / 4);
    vf4* __restrict__ dst = (vf4*)out_near + (size_t)(rowbase + r) * (DIM / 4);
#pragma unroll
    for (int j = 0; j < 4; ++j) {
      vf4 v = src[lane + 64 * j];
      __builtin_nontemporal_store(v, &dst[lane + 64 * j]);
    }
  }
}

// ---------------- Kernel 3: f64 re-resolution of razor-thin rows ----------------
__global__ __launch_bounds__(256) void k_refine(const float* __restrict__ x,
                                                const float* __restrict__ mem,
                                                const double* __restrict__ inv64,
                                                const unsigned int* __restrict__ flagbits,
                                                float* __restrict__ out_near) {
  unsigned int mask = flagbits[blockIdx.x];
  if (mask == 0u) return;                   // uniform; nearly all blocks exit
  const int tid = threadIdx.x;
  const int lane = tid & 63;
  const int wid = tid >> 6;
  __shared__ double bval[4];
  __shared__ int bidx[4];
  while (mask) {
    int r = __ffs(mask) - 1;
    mask &= (mask - 1u);
    int rrow = blockIdx.x * 16 + r;
    const float* __restrict__ xr = x + (size_t)rrow * DIM;
    double xd[16];
#pragma unroll
    for (int i = 0; i < 16; ++i) xd[i] = (double)xr[lane + 64 * i];
    double best = -1e300;
    int bi = 0;
    for (int q = 0; q < 10; ++q) {
      int m = wid * 10 + q;
      const float* __restrict__ mr = mem + (size_t)m * DIM;
      double s = 0.0;
#pragma unroll
      for (int i = 0; i < 16; ++i) s = fma(xd[i], (double)mr[lane + 64 * i], s);
#pragma unroll
      for (int off = 32; off > 0; off >>= 1) s += __shfl_xor(s, off, 64);
      double v = s * inv64[m];              // identical (bitwise) across lanes
      if (v > best) { best = v; bi = m; }   // strict > keeps lowest m on ties
    }
    if (lane == 0) { bval[wid] = best; bidx[wid] = bi; }
    __syncthreads();
    double g = bval[0];
    int gi = bidx[0];
#pragma unroll
    for (int gg = 1; gg < 4; ++gg) {
      if (bval[gg] > g) { g = bval[gg]; gi = bidx[gg]; }
    }
    const float4* __restrict__ src = (const float4*)mem + (size_t)gi * (DIM / 4);
    float4* __restrict__ dst = (float4*)out_near + (size_t)rrow * (DIM / 4);
    dst[tid] = src[tid];                    // 256 x 16B = full row, coalesced
    __syncthreads();                        // LDS reuse guard for next flagged row
  }
}

extern "C" void kernel_launch(void* const* d_in, const int* in_sizes, int n_in,
                              void* d_out, int out_size, void* d_ws, size_t ws_size,
                              hipStream_t stream) {
  const float* x   = (const float*)d_in[0];
  const float* mem = (const float*)d_in[1];
  // d_in[2] = top_k (unused: reference only consumes idx[:,0], i.e. the argmax)

  const int n_rows = in_sizes[0] / DIM;          // 65536
  float* out_near = (float*)d_out;
  float* out_x    = (float*)d_out + (size_t)n_rows * DIM;

  double* inv64 = (double*)d_ws;
  float*  inv32 = (float*)((char*)d_ws + 320);
  unsigned int* flagbits = (unsigned int*)((char*)d_ws + 512);
  unsigned short* bhi = (unsigned short*)((char*)d_ws + 32768);
  unsigned short* blo = (unsigned short*)((char*)d_ws + 131072);

  hipLaunchKernelGGL(k_norms, dim3(NMEM), dim3(64), 0, stream, mem, inv64, inv32);
  hipLaunchKernelGGL(k_prep,  dim3(48),   dim3(256), 0, stream, mem, inv32, bhi, blo);
  hipLaunchKernelGGL(k_main,  dim3(n_rows / 64), dim3(256), 0, stream,
                     x, mem, bhi, blo, out_near, out_x, flagbits);
  hipLaunchKernelGGL(k_refine, dim3(n_rows / 16), dim3(256), 0, stream,
                     x, mem, inv64, flagbits, out_near);
}